// Round 2
// baseline (148.687 us; speedup 1.0000x reference)
//
#include <hip/hip_runtime.h>

// PointNet++ set abstraction: ball query (first-16-by-index within r=0.5) +
// gather + relative-coords/feat concat + 2-layer MLP (leaky 0.1) + max-pool.
// B=4, N=16384, M=4096, K=16.  One wave (64 lanes) per query.
//
// Boundary-exact d2: sum-of-squares with plain rn mul/add (reference computes
// x**2 then sum as separate ops -> no FMA), dot product as ascending-k FMA
// chain (reference einsum lowers to llvm.fmuladd / BLAS fma microkernel).

constexpr int N_PTS = 16384;
constexpr int M_Q   = 4096;
constexpr int KNN   = 16;

__global__ __launch_bounds__(256) void pe_flow_fused_kernel(
    const float* __restrict__ xyz,   // (B, N, 3)
    const float* __restrict__ feat,  // (B, N, 3)
    const int*   __restrict__ fps,   // (B, M)
    const float* __restrict__ W1,    // (6, 32)
    const float* __restrict__ b1,    // (32)
    const float* __restrict__ W2,    // (32, 32)
    const float* __restrict__ b2,    // (32)
    float* __restrict__ out)         // (B, M, 32)
{
    __shared__ float sW1[192];
    __shared__ float sW2[1024];
    __shared__ float sb1[32];
    __shared__ float sb2[32];
    __shared__ int   sNbr[4][KNN];

    const int tid = threadIdx.x;
    if (tid < 192) sW1[tid] = W1[tid];
    for (int i = tid; i < 1024; i += 256) sW2[i] = W2[i];
    if (tid < 32) { sb1[tid] = b1[tid]; sb2[tid] = b2[tid]; }
    __syncthreads();

    const int wave = tid >> 6;
    const int lane = tid & 63;
    const int q = blockIdx.x * 4 + wave;      // global query id, 0..16383
    const int b = q >> 12;                    // q / 4096
    const int m = q & (M_Q - 1);

    const float* xb = xyz  + (size_t)b * N_PTS * 3;
    const float* fb = feat + (size_t)b * N_PTS * 3;

    const int pidx = fps[b * M_Q + m];
    const float qx = xb[pidx * 3 + 0];
    const float qy = xb[pidx * 3 + 1];
    const float qz = xb[pidx * 3 + 2];
    // sum(q**2): squares then left-assoc adds, NO fma (matches separate ops).
    const float sq_q = __fadd_rn(__fadd_rn(__fmul_rn(qx, qx), __fmul_rn(qy, qy)),
                                 __fmul_rn(qz, qz));

    // ---- ball query: first 16 in-radius indices in ascending order ----
    int count = 0;
    const unsigned long long lt_mask = (1ull << lane) - 1ull;
    for (int base = 0; base < N_PTS; base += 64) {
        const int i = base + lane;
        const float px = xb[i * 3 + 0];
        const float py = xb[i * 3 + 1];
        const float pz = xb[i * 3 + 2];
        const float sq_p = __fadd_rn(__fadd_rn(__fmul_rn(px, px), __fmul_rn(py, py)),
                                     __fmul_rn(pz, pz));
        // einsum dot: ascending-k FMA chain (llvm.fmuladd lowering).
        float dot = __fmul_rn(qx, px);
        dot = __builtin_fmaf(qy, py, dot);
        dot = __builtin_fmaf(qz, pz, dot);
        const float d2 = __fsub_rn(__fadd_rn(sq_q, sq_p), __fmul_rn(2.0f, dot));
        const bool hit = (d2 <= 0.25f);
        const unsigned long long mk = __ballot(hit);
        if (hit) {
            const int pos = count + __popcll(mk & lt_mask);
            if (pos < KNN) sNbr[wave][pos] = i;
        }
        count += (int)__popcll(mk);
        if (count >= KNN) break;   // wave-uniform
    }
    if (count < KNN) {
        // Guaranteed count >= 1 (the query point itself is at d2 == 0).
        const int first = sNbr[wave][0];
        if (lane >= count && lane < KNN) sNbr[wave][lane] = first;
    }

    // ---- fused MLP: 64 lanes = 16 neighbors x 4 channel-groups(8) ----
    const int k = lane >> 2;      // neighbor 0..15
    const int c = lane & 3;       // channel group 0..3
    const int co = c * 8;
    const int ni = sNbr[wave][k];

    const float in0 = xb[ni * 3 + 0] - qx;
    const float in1 = xb[ni * 3 + 1] - qy;
    const float in2 = xb[ni * 3 + 2] - qz;
    const float in3 = fb[ni * 3 + 0];
    const float in4 = fb[ni * 3 + 1];
    const float in5 = fb[ni * 3 + 2];

    float h1[8];
    #pragma unroll
    for (int i = 0; i < 8; ++i) {
        float a = sb1[co + i];
        a += in0 * sW1[0 * 32 + co + i];
        a += in1 * sW1[1 * 32 + co + i];
        a += in2 * sW1[2 * 32 + co + i];
        a += in3 * sW1[3 * 32 + co + i];
        a += in4 * sW1[4 * 32 + co + i];
        a += in5 * sW1[5 * 32 + co + i];
        h1[i] = (a >= 0.0f) ? a : 0.1f * a;
    }

    float h2[8];
    #pragma unroll
    for (int i = 0; i < 8; ++i) h2[i] = sb2[co + i];
    const int baseLane = lane & ~3;
    #pragma unroll
    for (int jj = 0; jj < 8; ++jj) {
        #pragma unroll
        for (int g = 0; g < 4; ++g) {
            const float v = __shfl(h1[jj], baseLane + g, 64);  // h1[row] of this neighbor
            const int row = g * 8 + jj;
            #pragma unroll
            for (int i = 0; i < 8; ++i)
                h2[i] += v * sW2[row * 32 + co + i];
        }
    }

    #pragma unroll
    for (int i = 0; i < 8; ++i) {
        float v = h2[i];
        v = (v >= 0.0f) ? v : 0.1f * v;
        // max over the 16 neighbors (lane bits 2..5), c stays fixed
        v = fmaxf(v, __shfl_xor(v, 4, 64));
        v = fmaxf(v, __shfl_xor(v, 8, 64));
        v = fmaxf(v, __shfl_xor(v, 16, 64));
        v = fmaxf(v, __shfl_xor(v, 32, 64));
        h2[i] = v;
    }

    if (k == 0) {
        float* op = out + (size_t)q * 32 + co;
        #pragma unroll
        for (int i = 0; i < 8; ++i) op[i] = h2[i];
    }
}

extern "C" void kernel_launch(void* const* d_in, const int* in_sizes, int n_in,
                              void* d_out, int out_size, void* d_ws, size_t ws_size,
                              hipStream_t stream) {
    const float* xyz  = (const float*)d_in[0];
    const float* feat = (const float*)d_in[1];
    const int*   fps  = (const int*)d_in[2];
    const float* W1   = (const float*)d_in[3];
    const float* b1   = (const float*)d_in[4];
    const float* W2   = (const float*)d_in[5];
    const float* b2   = (const float*)d_in[6];
    float* out = (float*)d_out;

    const int total_q = 4 * M_Q;          // 16384 queries
    dim3 grid(total_q / 4), block(256);   // 4 waves/block, 1 wave/query
    pe_flow_fused_kernel<<<grid, block, 0, stream>>>(xyz, feat, fps, W1, b1, W2, b2, out);
}